// Round 2
// baseline (488.795 us; speedup 1.0000x reference)
//
#include <hip/hip_runtime.h>
#include <hip/hip_bf16.h>
#include <math.h>

#define T_STEPS 8
#define F_IN 64
#define HC 128        // H*C = 2*64
#define C_OUT 64
#define NEG_SLOPE 0.2f

typedef _Float16 half8 __attribute__((ext_vector_type(8)));
typedef _Float16 half2v __attribute__((ext_vector_type(2)));
typedef float f32x4 __attribute__((ext_vector_type(4)));

// packed f16 dot: acc += a.x*b.x + a.y*b.y (f32 accumulate) — V_DOT2_F32_F16
static __device__ __forceinline__ float dot2(half2v a, half2v b, float c) {
    return __builtin_amdgcn_fdot2(a, b, c, false);
}

// ---------------- CSR build ----------------
__global__ void k_zero_i32(int* p, int n) {
    int i = blockIdx.x * blockDim.x + threadIdx.x;
    if (i < n) p[i] = 0;
}

__global__ void k_count(const int* __restrict__ dst, int* __restrict__ cnt, int E) {
    int e = blockIdx.x * blockDim.x + threadIdx.x;
    if (e < E) atomicAdd(&cnt[dst[e]], 1);
}

__global__ void k_scan1(int* data, int* bsum, int n) {
    __shared__ int tmp[256];
    int tid = threadIdx.x;
    int i = blockIdx.x * 256 + tid;
    int v = (i < n) ? data[i] : 0;
    tmp[tid] = v; __syncthreads();
    for (int off = 1; off < 256; off <<= 1) {
        int x = (tid >= off) ? tmp[tid - off] : 0;
        __syncthreads();
        tmp[tid] += x;
        __syncthreads();
    }
    if (i < n) data[i] = tmp[tid] - v;   // exclusive
    if (tid == 255) bsum[blockIdx.x] = tmp[255];
}

__global__ void k_scan2(int* bsum, int nb) {  // nb <= 256
    __shared__ int tmp[256];
    int tid = threadIdx.x;
    int v = (tid < nb) ? bsum[tid] : 0;
    tmp[tid] = v; __syncthreads();
    for (int off = 1; off < 256; off <<= 1) {
        int x = (tid >= off) ? tmp[tid - off] : 0;
        __syncthreads();
        tmp[tid] += x;
        __syncthreads();
    }
    if (tid < nb) bsum[tid] = tmp[tid] - v;
}

__global__ void k_scan3(int* data, const int* __restrict__ bsum, int* cursor, int n, int total) {
    int i = blockIdx.x * 256 + threadIdx.x;
    if (i < n) {
        int v = data[i] + bsum[i >> 8];
        data[i] = v;
        cursor[i] = v;
    }
    if (i == 0) data[n] = total;
}

__global__ void k_fill(const int* __restrict__ src, const int* __restrict__ dst,
                       int* __restrict__ cursor, int* __restrict__ csr_src, int E) {
    int e = blockIdx.x * blockDim.x + threadIdx.x;
    if (e < E) {
        int d = dst[e];
        int pos = atomicAdd(&cursor[d], 1);
        csr_src[pos] = src[e];
    }
}

// ---------------- WQ precompute: WQt[q][f] = sum_c W[f][head(q)*64+c]*att_q[c]
// q: 0=(src,h0) 1=(src,h1) 2=(dst,h0) 3=(dst,h1). Stored transposed [4][64] f16.
__global__ void k_wq(const float* __restrict__ W, const float* __restrict__ att_src,
                     const float* __restrict__ att_dst, _Float16* __restrict__ WQt) {
    int tid = threadIdx.x;         // 256 threads
    int q = tid & 3, f = tid >> 2; // f in 0..63
    const float* att = (q & 2) ? att_dst : att_src;
    int hh = q & 1;
    float s = 0.f;
    #pragma unroll 8
    for (int c = 0; c < 64; c++) s += W[f * HC + hh * 64 + c] * att[hh * 64 + c];
    WQt[q * 64 + f] = (_Float16)s;
}

// ---------------- GEMM via MFMA: xl = x_t @ W (fp16 head-interleaved) + scores
// blockIdx.y = timestep. 64 nodes x 128 cols per block, 4 waves (32 cols each).
// A/B fragments loaded straight from global (no LDS staging). Scores computed
// as one extra MFMA tile against the precomputed WQ matrix.
// mfma_f32_16x16x32_f16 layouts: A[row=lane%16][k=(lane/16)*8+j],
// B[k=(lane/16)*8+j][col=lane%16], D[col=lane&15][row=(lane>>4)*4+reg].
__global__ __launch_bounds__(256) void k_gemm(
    const float* __restrict__ h, const float* __restrict__ W,
    const _Float16* __restrict__ WQt,
    _Float16* __restrict__ xlh, float* __restrict__ a_s, float* __restrict__ a_d,
    int N)
{
    __shared__ _Float16 sOut[64 * HC];   // 16 KB staging for coalesced xlh store

    int tid = threadIdx.x;
    int t = blockIdx.y;
    int node0 = blockIdx.x * 64;
    int w = tid >> 6;          // wave 0..3 -> col slice w*32
    int lane = tid & 63;
    int cl = lane & 15;        // col within 16-wide tile / A row within tile
    int lg = lane >> 4;        // lane group 0..3 -> k chunk lg*8

    // ---- A fragments: af[rt][ks], rows node0+rt*16+cl, k = lg*8 + ks*32 + j
    half8 af[4][2];
    #pragma unroll
    for (int rt = 0; rt < 4; rt++) {
        int n = node0 + rt * 16 + cl;
        int nc = n < N ? n : N - 1;                 // clamp reads; stores guarded
        const float* hp = h + ((size_t)nc * T_STEPS + t) * F_IN + lg * 8;
        #pragma unroll
        for (int ks = 0; ks < 2; ks++) {
            f32x4 x0 = *(const f32x4*)(hp + ks * 32);
            f32x4 x1 = *(const f32x4*)(hp + ks * 32 + 4);
            half8 a;
            a[0] = (_Float16)x0[0]; a[1] = (_Float16)x0[1];
            a[2] = (_Float16)x0[2]; a[3] = (_Float16)x0[3];
            a[4] = (_Float16)x1[0]; a[5] = (_Float16)x1[1];
            a[6] = (_Float16)x1[2]; a[7] = (_Float16)x1[3];
            af[rt][ks] = a;
        }
    }

    // ---- B fragments: bf[ct][ks], col = w*32 + ct*16 + cl, k = lg*8 + ks*32 + j
    half8 bf[2][2];
    #pragma unroll
    for (int ct = 0; ct < 2; ct++) {
        int col = w * 32 + ct * 16 + cl;
        #pragma unroll
        for (int ks = 0; ks < 2; ks++) {
            half8 b;
            #pragma unroll
            for (int j = 0; j < 8; j++)
                b[j] = (_Float16)W[(size_t)(ks * 32 + lg * 8 + j) * HC + col];
            bf[ct][ks] = b;
        }
    }

    // ---- score B fragment: col = q (0..3), rest zero
    half8 bq[2];
    #pragma unroll
    for (int ks = 0; ks < 2; ks++) {
        half8 b = {};
        if (cl < 4) b = *(const half8*)&WQt[cl * 64 + lg * 8 + ks * 32];
        bq[ks] = b;
    }

    // ---- MFMA main: acc[rt][ct] over K=64 (2 steps)
    f32x4 acc[4][2];
    #pragma unroll
    for (int rt = 0; rt < 4; rt++)
        #pragma unroll
        for (int ct = 0; ct < 2; ct++) {
            f32x4 c = {0.f, 0.f, 0.f, 0.f};
            c = __builtin_amdgcn_mfma_f32_16x16x32_f16(af[rt][0], bf[ct][0], c, 0, 0, 0);
            c = __builtin_amdgcn_mfma_f32_16x16x32_f16(af[rt][1], bf[ct][1], c, 0, 0, 0);
            acc[rt][ct] = c;
        }

    // ---- score tile: wave w handles rowtile w
    f32x4 sacc = {0.f, 0.f, 0.f, 0.f};
    sacc = __builtin_amdgcn_mfma_f32_16x16x32_f16(af[w][0], bq[0], sacc, 0, 0, 0);
    sacc = __builtin_amdgcn_mfma_f32_16x16x32_f16(af[w][1], bq[1], sacc, 0, 0, 0);

    float* ast = a_s + (size_t)t * N * 2;
    float* adt = a_d + (size_t)t * N * 2;
    if (cl < 4) {
        float* basep = (cl & 2) ? adt : ast;
        #pragma unroll
        for (int reg = 0; reg < 4; reg++) {
            int n = node0 + w * 16 + lg * 4 + reg;
            if (n < N) basep[(size_t)n * 2 + (cl & 1)] = sacc[reg];
        }
    }

    // ---- stage xl into LDS in head-interleaved layout, then coalesced store
    #pragma unroll
    for (int rt = 0; rt < 4; rt++)
        #pragma unroll
        for (int ct = 0; ct < 2; ct++) {
            int col = w * 32 + ct * 16 + cl;
            int ei = (col & 63) * 2 + (col >> 6);
            #pragma unroll
            for (int reg = 0; reg < 4; reg++) {
                int row = rt * 16 + lg * 4 + reg;
                sOut[row * HC + ei] = (_Float16)acc[rt][ct][reg];
            }
        }
    __syncthreads();

    _Float16* xlt = xlh + (size_t)t * N * HC;
    #pragma unroll
    for (int it = 0; it < 4; it++) {
        int idx = it * 256 + tid;        // 1024 chunks of 8 f16
        int row = idx >> 4;
        int n = node0 + row;
        if (n < N)
            *(half8*)&xlt[(size_t)n * HC + (idx & 15) * 8] = *(half8*)&sOut[idx * 8];
    }
}

// ---------------- Edge softmax + aggregate ----------------------------------
// blockIdx.y = timestep. 4 nodes per wave (16 lanes each), width-16 butterflies.
// Edge descriptors {src, half2(w0,w1)} staged in LDS, padded to mult of 4 with
// zero-weight entries; aggregation unrolled x4 -> 4 independent gathers in
// flight. Per-edge math is a single v_dot2_f32_f16 (packed half2 value x
// packed half2 weight, f32 accumulate) instead of 4x cvt + 2x fma.
__global__ __launch_bounds__(256) void k_edge(
    const int* __restrict__ csr_row, const int* __restrict__ csr_src,
    const float* __restrict__ a_s, const float* __restrict__ a_d,
    const _Float16* __restrict__ xlh, const float* __restrict__ bias,
    float* __restrict__ out, int N)
{
    __shared__ int2 edata[16][16];   // [node_local][edge_j] = {src, half2(w0,w1)}

    int tid  = threadIdx.x;
    int lane = tid & 63;
    int wid  = tid >> 6;
    int grp  = lane >> 4;    // 0..3: node slot within wave
    int gl   = lane & 15;    // lane within group
    int t = blockIdx.y;
    const _Float16* xlt = xlh + (size_t)t * N * HC;
    const float* ast = a_s + (size_t)t * N * 2;
    const float* adt = a_d + (size_t)t * N * 2;

    int nodeBlock0 = blockIdx.x * 16;
    int node = nodeBlock0 + wid * 4 + grp;
    bool nvalid = node < N;

    int beg = 0, end = 0;
    if (nvalid) { beg = csr_row[node]; end = csr_row[node + 1]; }
    int deg = end - beg;

    float bs = bias[lane];

    if (__ballot(deg > 16) == 0ull) {
        // ---- fast path: deg <= 16 for all 4 nodes of this wave ----
        float2 adv = make_float2(0.f, 0.f);
        if (nvalid) adv = *(const float2*)&adt[(size_t)node * 2];

        int e = beg + gl;
        bool ev = nvalid && (e < end);
        int s = ev ? csr_src[e] : 0;
        float e0 = -1e30f, e1 = -1e30f;
        if (ev) {
            float2 asv = *(const float2*)&ast[(size_t)s * 2];
            e0 = asv.x + adv.x;
            e1 = asv.y + adv.y;
            e0 = e0 > 0.f ? e0 : NEG_SLOPE * e0;
            e1 = e1 > 0.f ? e1 : NEG_SLOPE * e1;
        }
        float m0 = e0, m1 = e1;
        #pragma unroll
        for (int off = 8; off >= 1; off >>= 1) {
            m0 = fmaxf(m0, __shfl_xor(m0, off));
            m1 = fmaxf(m1, __shfl_xor(m1, off));
        }
        float x0 = ev ? __expf(e0 - m0) : 0.f;
        float x1 = ev ? __expf(e1 - m1) : 0.f;
        float d0 = x0, d1 = x1;
        #pragma unroll
        for (int off = 8; off >= 1; off >>= 1) {
            d0 += __shfl_xor(d0, off);
            d1 += __shfl_xor(d1, off);
        }
        float w0 = x0 * (0.5f / d0);   // 0.5 = head-mean
        float w1 = x1 * (0.5f / d1);

        // all 16 slots written: invalid lanes write zero-weight entries (src 0)
        union { uint u; _Float16 hh[2]; } cw;
        cw.hh[0] = ev ? (_Float16)w0 : (_Float16)0.f;
        cw.hh[1] = ev ? (_Float16)w1 : (_Float16)0.f;
        edata[wid * 4 + grp][gl] = make_int2(ev ? s : 0, (int)cw.u);
        // wave-synchronous: same wave wrote the rows it reads below

        #pragma unroll
        for (int k = 0; k < 4; k++) {
            int nk = nodeBlock0 + wid * 4 + k;
            if (nk >= N) continue;
            int dk = __shfl(deg, k * 16);
            int dkr = (dk + 3) & ~3;          // padded entries have w=0
            float a0 = 0.f, a1 = 0.f;
            const int2* row = edata[wid * 4 + k];
            for (int j = 0; j < dkr; j += 4) {
                int4 p = *(const int4*)&row[j];       // edges j, j+1
                int4 q = *(const int4*)&row[j + 2];   // edges j+2, j+3
                half2v v0 = *(const half2v*)&xlt[(size_t)p.x * HC + lane * 2];
                half2v v1 = *(const half2v*)&xlt[(size_t)p.z * HC + lane * 2];
                half2v v2 = *(const half2v*)&xlt[(size_t)q.x * HC + lane * 2];
                half2v v3 = *(const half2v*)&xlt[(size_t)q.z * HC + lane * 2];
                union { int i; half2v h; } c0, c1, c2, c3;
                c0.i = p.y; c1.i = p.w;
                c2.i = q.y; c3.i = q.w;
                a0 = dot2(v0, c0.h, a0);
                a1 = dot2(v1, c1.h, a1);
                a0 = dot2(v2, c2.h, a0);
                a1 = dot2(v3, c3.h, a1);
            }
            float acc = a0 + a1 + bs;
            float o = acc > 0.f ? acc : expm1f(acc);
            out[((size_t)nk * T_STEPS + t) * C_OUT + lane] = o;
        }
    } else {
        // ---- generic path: 64-wide strided per node, 4 nodes sequentially ----
        #pragma unroll
        for (int k = 0; k < 4; k++) {
            int nk = nodeBlock0 + wid * 4 + k;
            if (nk >= N) continue;
            int bk = __shfl(beg, k * 16);
            int ek = __shfl(end, k * 16);
            float2 adv = *(const float2*)&adt[(size_t)nk * 2];

            float m0 = -1e30f, m1 = -1e30f;
            for (int e = bk + lane; e < ek; e += 64) {
                int s = csr_src[e];
                float2 asv = *(const float2*)&ast[(size_t)s * 2];
                float e0 = asv.x + adv.x, e1 = asv.y + adv.y;
                e0 = e0 > 0.f ? e0 : NEG_SLOPE * e0;
                e1 = e1 > 0.f ? e1 : NEG_SLOPE * e1;
                m0 = fmaxf(m0, e0); m1 = fmaxf(m1, e1);
            }
            #pragma unroll
            for (int off = 32; off >= 1; off >>= 1) {
                m0 = fmaxf(m0, __shfl_xor(m0, off));
                m1 = fmaxf(m1, __shfl_xor(m1, off));
            }
            float d0 = 0.f, d1 = 0.f;
            for (int e = bk + lane; e < ek; e += 64) {
                int s = csr_src[e];
                float2 asv = *(const float2*)&ast[(size_t)s * 2];
                float e0 = asv.x + adv.x, e1 = asv.y + adv.y;
                e0 = e0 > 0.f ? e0 : NEG_SLOPE * e0;
                e1 = e1 > 0.f ? e1 : NEG_SLOPE * e1;
                d0 += __expf(e0 - m0); d1 += __expf(e1 - m1);
            }
            #pragma unroll
            for (int off = 32; off >= 1; off >>= 1) {
                d0 += __shfl_xor(d0, off);
                d1 += __shfl_xor(d1, off);
            }
            float r0 = 0.5f / d0, r1 = 0.5f / d1;

            float a0 = 0.f, a1 = 0.f;
            for (int base = bk; base < ek; base += 64) {
                int e = base + lane;
                int cnt = min(64, ek - base);
                int s = 0;
                union { uint u; _Float16 hh[2]; } cw;
                cw.u = 0u;
                if (e < ek) {
                    s = csr_src[e];
                    float2 asv = *(const float2*)&ast[(size_t)s * 2];
                    float e0 = asv.x + adv.x, e1 = asv.y + adv.y;
                    e0 = e0 > 0.f ? e0 : NEG_SLOPE * e0;
                    e1 = e1 > 0.f ? e1 : NEG_SLOPE * e1;
                    cw.hh[0] = (_Float16)(__expf(e0 - m0) * r0);
                    cw.hh[1] = (_Float16)(__expf(e1 - m1) * r1);
                }
                int wv = (int)cw.u;
                for (int j = 0; j < cnt; j++) {
                    int sj = __shfl(s, j);
                    int wj = __shfl(wv, j);
                    union { int i; half2v h; } c; c.i = wj;
                    half2v v = *(const half2v*)&xlt[(size_t)sj * HC + lane * 2];
                    a0 = dot2(v, c.h, a0);
                }
            }
            float acc = a0 + a1 + bs;
            float o = acc > 0.f ? acc : expm1f(acc);
            out[((size_t)nk * T_STEPS + t) * C_OUT + lane] = o;
        }
    }
}

// ---------------- launcher ----------------
extern "C" void kernel_launch(void* const* d_in, const int* in_sizes, int n_in,
                              void* d_out, int out_size, void* d_ws, size_t ws_size,
                              hipStream_t stream)
{
    const float* h       = (const float*)d_in[0];
    const int*   src     = (const int*)d_in[1];
    const int*   dst     = (const int*)d_in[2];
    const float* W       = (const float*)d_in[3];
    const float* att_src = (const float*)d_in[4];
    const float* att_dst = (const float*)d_in[5];
    const float* bias    = (const float*)d_in[6];
    float* out = (float*)d_out;

    int N = in_sizes[0] / (T_STEPS * F_IN);
    int E = in_sizes[1];

    char* wsb = (char*)d_ws;
    size_t off = 0;
    auto alloc = [&](size_t bytes) -> char* {
        off = (off + 255) & ~(size_t)255;
        char* p = wsb + off;
        off += bytes;
        return p;
    };

    int* csr_row = (int*)alloc((size_t)(N + 1) * sizeof(int));
    int* cursor  = (int*)alloc((size_t)N * sizeof(int));
    int* bsum    = (int*)alloc(1024 * sizeof(int));
    int* csr_src = (int*)alloc((size_t)E * sizeof(int));
    float* a_s   = (float*)alloc((size_t)T_STEPS * N * 2 * sizeof(float));
    float* a_d   = (float*)alloc((size_t)T_STEPS * N * 2 * sizeof(float));
    _Float16* WQt = (_Float16*)alloc(4 * 64 * sizeof(_Float16));
    _Float16* xlh = (_Float16*)alloc((size_t)T_STEPS * N * HC * sizeof(_Float16));
    // total ~110 MB; all-t fp16 xlh (102 MB) fits L3 (256 MB)

    int nb = (N + 255) / 256;
    k_zero_i32<<<(N + 1 + 255) / 256, 256, 0, stream>>>(csr_row, N + 1);
    k_count<<<(E + 255) / 256, 256, 0, stream>>>(dst, csr_row, E);
    k_scan1<<<nb, 256, 0, stream>>>(csr_row, bsum, N);
    k_scan2<<<1, 256, 0, stream>>>(bsum, nb);
    k_scan3<<<nb, 256, 0, stream>>>(csr_row, bsum, cursor, N, E);
    k_fill<<<(E + 255) / 256, 256, 0, stream>>>(src, dst, cursor, csr_src, E);

    k_wq<<<1, 256, 0, stream>>>(W, att_src, att_dst, WQt);
    dim3 gg((N + 63) / 64, T_STEPS);
    k_gemm<<<gg, 256, 0, stream>>>(h, W, WQt, xlh, a_s, a_d, N);
    dim3 ge((N + 15) / 16, T_STEPS);
    k_edge<<<ge, 256, 0, stream>>>(csr_row, csr_src, a_s, a_d, xlh, bias, out, N);
}

// Round 4
// 443.931 us; speedup vs baseline: 1.1011x; 1.1011x over previous
//
#include <hip/hip_runtime.h>
#include <hip/hip_bf16.h>
#include <math.h>

#define T_STEPS 8
#define F_IN 64
#define HC 128        // H*C = 2*64
#define C_OUT 64
#define NEG_SLOPE 0.2f

typedef _Float16 half8 __attribute__((ext_vector_type(8)));
typedef _Float16 half2v __attribute__((ext_vector_type(2)));
typedef float f32x4 __attribute__((ext_vector_type(4)));

// packed f16 dot: acc += a.x*b.x + a.y*b.y (f32 accumulate) — V_DOT2_F32_F16
static __device__ __forceinline__ float dot2(half2v a, half2v b, float c) {
    return __builtin_amdgcn_fdot2(a, b, c, false);
}

// ---------------- CSR build ----------------
__global__ void k_zero_i32(int* p, int n) {
    int i = blockIdx.x * blockDim.x + threadIdx.x;
    if (i < n) p[i] = 0;
}

__global__ void k_count(const int* __restrict__ dst, int* __restrict__ cnt, int E) {
    int e = blockIdx.x * blockDim.x + threadIdx.x;
    if (e < E) atomicAdd(&cnt[dst[e]], 1);
}

__global__ void k_scan1(int* data, int* bsum, int n) {
    __shared__ int tmp[256];
    int tid = threadIdx.x;
    int i = blockIdx.x * 256 + tid;
    int v = (i < n) ? data[i] : 0;
    tmp[tid] = v; __syncthreads();
    for (int off = 1; off < 256; off <<= 1) {
        int x = (tid >= off) ? tmp[tid - off] : 0;
        __syncthreads();
        tmp[tid] += x;
        __syncthreads();
    }
    if (i < n) data[i] = tmp[tid] - v;   // exclusive
    if (tid == 255) bsum[blockIdx.x] = tmp[255];
}

__global__ void k_scan2(int* bsum, int nb) {  // nb <= 256
    __shared__ int tmp[256];
    int tid = threadIdx.x;
    int v = (tid < nb) ? bsum[tid] : 0;
    tmp[tid] = v; __syncthreads();
    for (int off = 1; off < 256; off <<= 1) {
        int x = (tid >= off) ? tmp[tid - off] : 0;
        __syncthreads();
        tmp[tid] += x;
        __syncthreads();
    }
    if (tid < nb) bsum[tid] = tmp[tid] - v;
}

__global__ void k_scan3(int* data, const int* __restrict__ bsum, int* cursor, int n, int total) {
    int i = blockIdx.x * 256 + threadIdx.x;
    if (i < n) {
        int v = data[i] + bsum[i >> 8];
        data[i] = v;
        cursor[i] = v;
    }
    if (i == 0) data[n] = total;
}

__global__ void k_fill(const int* __restrict__ src, const int* __restrict__ dst,
                       int* __restrict__ cursor, int* __restrict__ csr_src, int E) {
    int e = blockIdx.x * blockDim.x + threadIdx.x;
    if (e < E) {
        int d = dst[e];
        int pos = atomicAdd(&cursor[d], 1);
        csr_src[pos] = src[e];
    }
}

// ---------------- prep: WQt [4][64] f16 and Wt [128][64] f16 ----------------
// WQt[q][f] = sum_c W[f][head(q)*64+c]*att_q[c]; q: 0=(s,h0) 1=(s,h1) 2=(d,h0) 3=(d,h1)
// Wt[ei][k] = W[k][ (ei&1)*64 + (ei>>1) ]  (head-interleaved output slot ei)
__global__ void k_prep(const float* __restrict__ W, const float* __restrict__ att_src,
                       const float* __restrict__ att_dst,
                       _Float16* __restrict__ Wt, _Float16* __restrict__ WQt) {
    int tid = threadIdx.x;         // 256 threads
    {
        int q = tid & 3, f = tid >> 2; // f in 0..63
        const float* att = (q & 2) ? att_dst : att_src;
        int hh = q & 1;
        float s = 0.f;
        #pragma unroll 8
        for (int c = 0; c < 64; c++) s += W[f * HC + hh * 64 + c] * att[hh * 64 + c];
        WQt[q * 64 + f] = (_Float16)s;
    }
    for (int i = tid; i < 64 * HC; i += 256) {
        int ei = i >> 6, k = i & 63;
        Wt[i] = (_Float16)W[k * HC + (ei & 1) * 64 + (ei >> 1)];
    }
}

// ---------------- GEMM via MFMA: xl = x_t @ W (fp16 head-interleaved) + scores
// blockIdx.y = timestep. 64 nodes x 128 slots per block, 4 waves (32 slots each).
// A staged once through LDS (f16, 72-pad), B fragments = vector loads from the
// precomputed Wt (L1-resident). Output staged in 136-pad LDS (<=2-way banks).
// mfma_f32_16x16x32_f16: A[row=lane%16][k=(lane/16)*8+j],
// B[k=(lane/16)*8+j][col=lane%16], D[col=lane&15][row=(lane>>4)*4+reg].
__global__ __launch_bounds__(256) void k_gemm(
    const float* __restrict__ h, const _Float16* __restrict__ Wt,
    const _Float16* __restrict__ WQt,
    _Float16* __restrict__ xlh, float* __restrict__ a_s, float* __restrict__ a_d,
    int N)
{
    __shared__ _Float16 smem[64 * 136];  // 17408 B, overlaid: sA [64][72] then sOut [64][136]
    _Float16* sA   = smem;
    _Float16* sOut = smem;

    int tid = threadIdx.x;
    int t = blockIdx.y;
    int node0 = blockIdx.x * 64;
    int w = tid >> 6;          // wave 0..3 -> slot slice w*32
    int lane = tid & 63;
    int cl = lane & 15;
    int lg = lane >> 4;

    // ---- stage A: h[node0+row][t][k] -> f16 sA[row][k], row pad 72
    {
        int row = tid >> 2;
        int k0 = (tid & 3) * 16;
        int n = node0 + row;
        int nc = n < N ? n : N - 1;          // clamp reads; stores guarded later
        const float* hp = h + ((size_t)nc * T_STEPS + t) * F_IN + k0;
        f32x4 x0 = *(const f32x4*)(hp);
        f32x4 x1 = *(const f32x4*)(hp + 4);
        f32x4 x2 = *(const f32x4*)(hp + 8);
        f32x4 x3 = *(const f32x4*)(hp + 12);
        half8 p0, p1;
        p0[0] = (_Float16)x0[0]; p0[1] = (_Float16)x0[1];
        p0[2] = (_Float16)x0[2]; p0[3] = (_Float16)x0[3];
        p0[4] = (_Float16)x1[0]; p0[5] = (_Float16)x1[1];
        p0[6] = (_Float16)x1[2]; p0[7] = (_Float16)x1[3];
        p1[0] = (_Float16)x2[0]; p1[1] = (_Float16)x2[1];
        p1[2] = (_Float16)x2[2]; p1[3] = (_Float16)x2[3];
        p1[4] = (_Float16)x3[0]; p1[5] = (_Float16)x3[1];
        p1[6] = (_Float16)x3[2]; p1[7] = (_Float16)x3[3];
        *(half8*)&sA[row * 72 + k0]     = p0;
        *(half8*)&sA[row * 72 + k0 + 8] = p1;
    }
    __syncthreads();

    // ---- A fragments from LDS: rows rt*16+cl, k = ks*32 + lg*8 + j
    half8 af[4][2];
    #pragma unroll
    for (int rt = 0; rt < 4; rt++)
        #pragma unroll
        for (int ks = 0; ks < 2; ks++)
            af[rt][ks] = *(half8*)&sA[(rt * 16 + cl) * 72 + ks * 32 + lg * 8];

    // ---- B fragments from Wt: slot = w*32 + ct*16 + cl
    half8 bf[2][2];
    #pragma unroll
    for (int ct = 0; ct < 2; ct++)
        #pragma unroll
        for (int ks = 0; ks < 2; ks++)
            bf[ct][ks] = *(const half8*)&Wt[(size_t)(w * 32 + ct * 16 + cl) * 64 + ks * 32 + lg * 8];

    // ---- score B fragment: col = q (0..3), rest zero
    half8 bq[2];
    #pragma unroll
    for (int ks = 0; ks < 2; ks++) {
        half8 b = {};
        if (cl < 4) b = *(const half8*)&WQt[cl * 64 + ks * 32 + lg * 8];
        bq[ks] = b;
    }

    __syncthreads();   // all A reads drained; smem is reusable as sOut

    // ---- MFMA main; D col index == output slot ei directly (Wt permuted)
    #pragma unroll
    for (int rt = 0; rt < 4; rt++)
        #pragma unroll
        for (int ct = 0; ct < 2; ct++) {
            f32x4 c = {0.f, 0.f, 0.f, 0.f};
            c = __builtin_amdgcn_mfma_f32_16x16x32_f16(af[rt][0], bf[ct][0], c, 0, 0, 0);
            c = __builtin_amdgcn_mfma_f32_16x16x32_f16(af[rt][1], bf[ct][1], c, 0, 0, 0);
            int slot = w * 32 + ct * 16 + cl;
            #pragma unroll
            for (int reg = 0; reg < 4; reg++)
                sOut[(rt * 16 + lg * 4 + reg) * 136 + slot] = (_Float16)c[reg];
        }

    // ---- score tile: wave w handles rowtile w
    f32x4 sacc = {0.f, 0.f, 0.f, 0.f};
    sacc = __builtin_amdgcn_mfma_f32_16x16x32_f16(af[w][0], bq[0], sacc, 0, 0, 0);
    sacc = __builtin_amdgcn_mfma_f32_16x16x32_f16(af[w][1], bq[1], sacc, 0, 0, 0);

    float* ast = a_s + (size_t)t * N * 2;
    float* adt = a_d + (size_t)t * N * 2;
    if (cl < 4) {
        float* basep = (cl & 2) ? adt : ast;
        #pragma unroll
        for (int reg = 0; reg < 4; reg++) {
            int n = node0 + w * 16 + lg * 4 + reg;
            if (n < N) basep[(size_t)n * 2 + (cl & 1)] = sacc[reg];
        }
    }

    __syncthreads();

    // ---- coalesced store of xlh from sOut
    _Float16* xlt = xlh + (size_t)t * N * HC;
    #pragma unroll
    for (int it = 0; it < 4; it++) {
        int idx = it * 256 + tid;        // 1024 chunks of 8 f16
        int row = idx >> 4;
        int seg = idx & 15;
        int n = node0 + row;
        if (n < N)
            *(half8*)&xlt[(size_t)n * HC + seg * 8] = *(half8*)&sOut[row * 136 + seg * 8];
    }
}

// ---------------- Edge softmax + aggregate ----------------------------------
// blockIdx.y = timestep. 4 nodes per wave (16 lanes each), width-16 butterflies.
// Edge descriptors {src, half2(w0,w1)} staged in LDS, padded to mult of 4 with
// zero-weight entries; aggregation unrolled x4 -> 4 independent gathers in
// flight. Per-edge math is a single v_dot2_f32_f16.
__global__ __launch_bounds__(256) void k_edge(
    const int* __restrict__ csr_row, const int* __restrict__ csr_src,
    const float* __restrict__ a_s, const float* __restrict__ a_d,
    const _Float16* __restrict__ xlh, const float* __restrict__ bias,
    float* __restrict__ out, int N)
{
    __shared__ int2 edata[16][16];   // [node_local][edge_j] = {src, half2(w0,w1)}

    int tid  = threadIdx.x;
    int lane = tid & 63;
    int wid  = tid >> 6;
    int grp  = lane >> 4;    // 0..3: node slot within wave
    int gl   = lane & 15;    // lane within group
    int t = blockIdx.y;
    const _Float16* xlt = xlh + (size_t)t * N * HC;
    const float* ast = a_s + (size_t)t * N * 2;
    const float* adt = a_d + (size_t)t * N * 2;

    int nodeBlock0 = blockIdx.x * 16;
    int node = nodeBlock0 + wid * 4 + grp;
    bool nvalid = node < N;

    int beg = 0, end = 0;
    if (nvalid) { beg = csr_row[node]; end = csr_row[node + 1]; }
    int deg = end - beg;

    float bs = bias[lane];

    if (__ballot(deg > 16) == 0ull) {
        // ---- fast path: deg <= 16 for all 4 nodes of this wave ----
        float2 adv = make_float2(0.f, 0.f);
        if (nvalid) adv = *(const float2*)&adt[(size_t)node * 2];

        int e = beg + gl;
        bool ev = nvalid && (e < end);
        int s = ev ? csr_src[e] : 0;
        float e0 = -1e30f, e1 = -1e30f;
        if (ev) {
            float2 asv = *(const float2*)&ast[(size_t)s * 2];
            e0 = asv.x + adv.x;
            e1 = asv.y + adv.y;
            e0 = e0 > 0.f ? e0 : NEG_SLOPE * e0;
            e1 = e1 > 0.f ? e1 : NEG_SLOPE * e1;
        }
        float m0 = e0, m1 = e1;
        #pragma unroll
        for (int off = 8; off >= 1; off >>= 1) {
            m0 = fmaxf(m0, __shfl_xor(m0, off));
            m1 = fmaxf(m1, __shfl_xor(m1, off));
        }
        float x0 = ev ? __expf(e0 - m0) : 0.f;
        float x1 = ev ? __expf(e1 - m1) : 0.f;
        float d0 = x0, d1 = x1;
        #pragma unroll
        for (int off = 8; off >= 1; off >>= 1) {
            d0 += __shfl_xor(d0, off);
            d1 += __shfl_xor(d1, off);
        }
        float w0 = x0 * (0.5f / d0);   // 0.5 = head-mean
        float w1 = x1 * (0.5f / d1);

        // all 16 slots written: invalid lanes write zero-weight entries (src 0)
        union { uint u; _Float16 hh[2]; } cw;
        cw.hh[0] = ev ? (_Float16)w0 : (_Float16)0.f;
        cw.hh[1] = ev ? (_Float16)w1 : (_Float16)0.f;
        edata[wid * 4 + grp][gl] = make_int2(ev ? s : 0, (int)cw.u);
        // wave-synchronous: same wave wrote the rows it reads below

        #pragma unroll
        for (int k = 0; k < 4; k++) {
            int nk = nodeBlock0 + wid * 4 + k;
            if (nk >= N) continue;
            int dk = __shfl(deg, k * 16);
            int dkr = (dk + 3) & ~3;          // padded entries have w=0
            float a0 = 0.f, a1 = 0.f;
            const int2* row = edata[wid * 4 + k];
            for (int j = 0; j < dkr; j += 4) {
                int4 p = *(const int4*)&row[j];       // edges j, j+1
                int4 q = *(const int4*)&row[j + 2];   // edges j+2, j+3
                half2v v0 = *(const half2v*)&xlt[(size_t)p.x * HC + lane * 2];
                half2v v1 = *(const half2v*)&xlt[(size_t)p.z * HC + lane * 2];
                half2v v2 = *(const half2v*)&xlt[(size_t)q.x * HC + lane * 2];
                half2v v3 = *(const half2v*)&xlt[(size_t)q.z * HC + lane * 2];
                union { int i; half2v h; } c0, c1, c2, c3;
                c0.i = p.y; c1.i = p.w;
                c2.i = q.y; c3.i = q.w;
                a0 = dot2(v0, c0.h, a0);
                a1 = dot2(v1, c1.h, a1);
                a0 = dot2(v2, c2.h, a0);
                a1 = dot2(v3, c3.h, a1);
            }
            float acc = a0 + a1 + bs;
            float o = acc > 0.f ? acc : expm1f(acc);
            out[((size_t)nk * T_STEPS + t) * C_OUT + lane] = o;
        }
    } else {
        // ---- generic path: 64-wide strided per node, 4 nodes sequentially ----
        #pragma unroll
        for (int k = 0; k < 4; k++) {
            int nk = nodeBlock0 + wid * 4 + k;
            if (nk >= N) continue;
            int bk = __shfl(beg, k * 16);
            int ek = __shfl(end, k * 16);
            float2 adv = *(const float2*)&adt[(size_t)nk * 2];

            float m0 = -1e30f, m1 = -1e30f;
            for (int e = bk + lane; e < ek; e += 64) {
                int s = csr_src[e];
                float2 asv = *(const float2*)&ast[(size_t)s * 2];
                float e0 = asv.x + adv.x, e1 = asv.y + adv.y;
                e0 = e0 > 0.f ? e0 : NEG_SLOPE * e0;
                e1 = e1 > 0.f ? e1 : NEG_SLOPE * e1;
                m0 = fmaxf(m0, e0); m1 = fmaxf(m1, e1);
            }
            #pragma unroll
            for (int off = 32; off >= 1; off >>= 1) {
                m0 = fmaxf(m0, __shfl_xor(m0, off));
                m1 = fmaxf(m1, __shfl_xor(m1, off));
            }
            float d0 = 0.f, d1 = 0.f;
            for (int e = bk + lane; e < ek; e += 64) {
                int s = csr_src[e];
                float2 asv = *(const float2*)&ast[(size_t)s * 2];
                float e0 = asv.x + adv.x, e1 = asv.y + adv.y;
                e0 = e0 > 0.f ? e0 : NEG_SLOPE * e0;
                e1 = e1 > 0.f ? e1 : NEG_SLOPE * e1;
                d0 += __expf(e0 - m0); d1 += __expf(e1 - m1);
            }
            #pragma unroll
            for (int off = 32; off >= 1; off >>= 1) {
                d0 += __shfl_xor(d0, off);
                d1 += __shfl_xor(d1, off);
            }
            float r0 = 0.5f / d0, r1 = 0.5f / d1;

            float a0 = 0.f, a1 = 0.f;
            for (int base = bk; base < ek; base += 64) {
                int e = base + lane;
                int cnt = min(64, ek - base);
                int s = 0;
                union { uint u; _Float16 hh[2]; } cw;
                cw.u = 0u;
                if (e < ek) {
                    s = csr_src[e];
                    float2 asv = *(const float2*)&ast[(size_t)s * 2];
                    float e0 = asv.x + adv.x, e1 = asv.y + adv.y;
                    e0 = e0 > 0.f ? e0 : NEG_SLOPE * e0;
                    e1 = e1 > 0.f ? e1 : NEG_SLOPE * e1;
                    cw.hh[0] = (_Float16)(__expf(e0 - m0) * r0);
                    cw.hh[1] = (_Float16)(__expf(e1 - m1) * r1);
                }
                int wv = (int)cw.u;
                for (int j = 0; j < cnt; j++) {
                    int sj = __shfl(s, j);
                    int wj = __shfl(wv, j);
                    union { int i; half2v h; } c; c.i = wj;
                    half2v v = *(const half2v*)&xlt[(size_t)sj * HC + lane * 2];
                    a0 = dot2(v, c.h, a0);
                }
            }
            float acc = a0 + a1 + bs;
            float o = acc > 0.f ? acc : expm1f(acc);
            out[((size_t)nk * T_STEPS + t) * C_OUT + lane] = o;
        }
    }
}

// ---------------- launcher ----------------
extern "C" void kernel_launch(void* const* d_in, const int* in_sizes, int n_in,
                              void* d_out, int out_size, void* d_ws, size_t ws_size,
                              hipStream_t stream)
{
    const float* h       = (const float*)d_in[0];
    const int*   src     = (const int*)d_in[1];
    const int*   dst     = (const int*)d_in[2];
    const float* W       = (const float*)d_in[3];
    const float* att_src = (const float*)d_in[4];
    const float* att_dst = (const float*)d_in[5];
    const float* bias    = (const float*)d_in[6];
    float* out = (float*)d_out;

    int N = in_sizes[0] / (T_STEPS * F_IN);
    int E = in_sizes[1];

    char* wsb = (char*)d_ws;
    size_t off = 0;
    auto alloc = [&](size_t bytes) -> char* {
        off = (off + 255) & ~(size_t)255;
        char* p = wsb + off;
        off += bytes;
        return p;
    };

    int* csr_row = (int*)alloc((size_t)(N + 1) * sizeof(int));
    int* cursor  = (int*)alloc((size_t)N * sizeof(int));
    int* bsum    = (int*)alloc(1024 * sizeof(int));
    int* csr_src = (int*)alloc((size_t)E * sizeof(int));
    float* a_s   = (float*)alloc((size_t)T_STEPS * N * 2 * sizeof(float));
    float* a_d   = (float*)alloc((size_t)T_STEPS * N * 2 * sizeof(float));
    _Float16* Wt  = (_Float16*)alloc((size_t)HC * 64 * sizeof(_Float16));
    _Float16* WQt = (_Float16*)alloc(4 * 64 * sizeof(_Float16));
    _Float16* xlh = (_Float16*)alloc((size_t)T_STEPS * N * HC * sizeof(_Float16));
    // total ~110 MB; all-t fp16 xlh (102 MB) fits L3 (256 MB)

    int nb = (N + 255) / 256;
    k_zero_i32<<<(N + 1 + 255) / 256, 256, 0, stream>>>(csr_row, N + 1);
    k_count<<<(E + 255) / 256, 256, 0, stream>>>(dst, csr_row, E);
    k_scan1<<<nb, 256, 0, stream>>>(csr_row, bsum, N);
    k_scan2<<<1, 256, 0, stream>>>(bsum, nb);
    k_scan3<<<nb, 256, 0, stream>>>(csr_row, bsum, cursor, N, E);
    k_fill<<<(E + 255) / 256, 256, 0, stream>>>(src, dst, cursor, csr_src, E);

    k_prep<<<1, 256, 0, stream>>>(W, att_src, att_dst, Wt, WQt);
    dim3 gg((N + 63) / 64, T_STEPS);
    k_gemm<<<gg, 256, 0, stream>>>(h, Wt, WQt, xlh, a_s, a_d, N);
    dim3 ge((N + 15) / 16, T_STEPS);
    k_edge<<<ge, 256, 0, stream>>>(csr_row, csr_src, a_s, a_d, xlh, bias, out, N);
}

// Round 5
// 439.848 us; speedup vs baseline: 1.1113x; 1.0093x over previous
//
#include <hip/hip_runtime.h>
#include <hip/hip_bf16.h>
#include <math.h>

#define T_STEPS 8
#define F_IN 64
#define HC 128        // H*C = 2*64
#define C_OUT 64
#define NEG_SLOPE 0.2f

typedef _Float16 half8 __attribute__((ext_vector_type(8)));
typedef _Float16 half2v __attribute__((ext_vector_type(2)));
typedef float f32x4 __attribute__((ext_vector_type(4)));

// packed f16 dot: acc += a.x*b.x + a.y*b.y (f32 accumulate) — V_DOT2_F32_F16
static __device__ __forceinline__ float dot2(half2v a, half2v b, float c) {
    return __builtin_amdgcn_fdot2(a, b, c, false);
}

// ---------------- CSR build ----------------
__global__ void k_zero_i32(int* p, int n) {
    int i = blockIdx.x * blockDim.x + threadIdx.x;
    if (i < n) p[i] = 0;
}

__global__ void k_count(const int* __restrict__ dst, int* __restrict__ cnt, int E) {
    int e = blockIdx.x * blockDim.x + threadIdx.x;
    if (e < E) atomicAdd(&cnt[dst[e]], 1);
}

__global__ void k_scan1(int* data, int* bsum, int n) {
    __shared__ int tmp[256];
    int tid = threadIdx.x;
    int i = blockIdx.x * 256 + tid;
    int v = (i < n) ? data[i] : 0;
    tmp[tid] = v; __syncthreads();
    for (int off = 1; off < 256; off <<= 1) {
        int x = (tid >= off) ? tmp[tid - off] : 0;
        __syncthreads();
        tmp[tid] += x;
        __syncthreads();
    }
    if (i < n) data[i] = tmp[tid] - v;   // exclusive
    if (tid == 255) bsum[blockIdx.x] = tmp[255];
}

__global__ void k_scan2(int* bsum, int nb) {  // nb <= 256
    __shared__ int tmp[256];
    int tid = threadIdx.x;
    int v = (tid < nb) ? bsum[tid] : 0;
    tmp[tid] = v; __syncthreads();
    for (int off = 1; off < 256; off <<= 1) {
        int x = (tid >= off) ? tmp[tid - off] : 0;
        __syncthreads();
        tmp[tid] += x;
        __syncthreads();
    }
    if (tid < nb) bsum[tid] = tmp[tid] - v;
}

__global__ void k_scan3(int* data, const int* __restrict__ bsum, int* cursor, int n, int total) {
    int i = blockIdx.x * 256 + threadIdx.x;
    if (i < n) {
        int v = data[i] + bsum[i >> 8];
        data[i] = v;
        cursor[i] = v;
    }
    if (i == 0) data[n] = total;
}

__global__ void k_fill(const int* __restrict__ src, const int* __restrict__ dst,
                       int* __restrict__ cursor, int* __restrict__ csr_src, int E) {
    int e = blockIdx.x * blockDim.x + threadIdx.x;
    if (e < E) {
        int d = dst[e];
        int pos = atomicAdd(&cursor[d], 1);
        csr_src[pos] = src[e];
    }
}

// ---------------- prep: WQt [4][64] f16 and Wt [128][64] f16 ----------------
// WQt[q][f] = sum_c W[f][head(q)*64+c]*att_q[c]; q: 0=(s,h0) 1=(s,h1) 2=(d,h0) 3=(d,h1)
// Wt[ei][k] = W[k][ (ei&1)*64 + (ei>>1) ]  (head-interleaved output slot ei)
// 33 blocks: block 0 -> WQt, blocks 1..32 -> Wt (256 elements each)
__global__ void k_prep(const float* __restrict__ W, const float* __restrict__ att_src,
                       const float* __restrict__ att_dst,
                       _Float16* __restrict__ Wt, _Float16* __restrict__ WQt) {
    int b = blockIdx.x;
    int tid = threadIdx.x;         // 256 threads
    if (b == 0) {
        int q = tid & 3, f = tid >> 2; // f in 0..63
        const float* att = (q & 2) ? att_dst : att_src;
        int hh = q & 1;
        float s = 0.f;
        #pragma unroll 8
        for (int c = 0; c < 64; c++) s += W[f * HC + hh * 64 + c] * att[hh * 64 + c];
        WQt[q * 64 + f] = (_Float16)s;
    } else {
        int i = (b - 1) * 256 + tid;   // 32*256 = 8192 = 64*HC
        int ei = i >> 6, k = i & 63;
        Wt[i] = (_Float16)W[k * HC + (ei & 1) * 64 + (ei >> 1)];
    }
}

// ---------------- GEMM via MFMA: xl = x_t @ W (fp16 head-interleaved) + scores
// blockIdx.y = timestep. 64 nodes x 128 slots per block, 4 waves (32 slots each).
// A staged once through LDS (f16, 72-pad), B fragments = vector loads from the
// precomputed Wt (L1-resident). Output staged in 136-pad LDS (<=2-way banks).
// mfma_f32_16x16x32_f16: A[row=lane%16][k=(lane/16)*8+j],
// B[k=(lane/16)*8+j][col=lane%16], D[col=lane&15][row=(lane>>4)*4+reg].
__global__ __launch_bounds__(256) void k_gemm(
    const float* __restrict__ h, const _Float16* __restrict__ Wt,
    const _Float16* __restrict__ WQt,
    _Float16* __restrict__ xlh, float* __restrict__ a_s, float* __restrict__ a_d,
    int N)
{
    __shared__ _Float16 smem[64 * 136];  // 17408 B, overlaid: sA [64][72] then sOut [64][136]
    _Float16* sA   = smem;
    _Float16* sOut = smem;

    int tid = threadIdx.x;
    int t = blockIdx.y;
    int node0 = blockIdx.x * 64;
    int w = tid >> 6;          // wave 0..3 -> slot slice w*32
    int lane = tid & 63;
    int cl = lane & 15;
    int lg = lane >> 4;

    // ---- stage A: h[node0+row][t][k] -> f16 sA[row][k], row pad 72
    {
        int row = tid >> 2;
        int k0 = (tid & 3) * 16;
        int n = node0 + row;
        int nc = n < N ? n : N - 1;          // clamp reads; stores guarded later
        const float* hp = h + ((size_t)nc * T_STEPS + t) * F_IN + k0;
        f32x4 x0 = __builtin_nontemporal_load((const f32x4*)(hp));
        f32x4 x1 = __builtin_nontemporal_load((const f32x4*)(hp + 4));
        f32x4 x2 = __builtin_nontemporal_load((const f32x4*)(hp + 8));
        f32x4 x3 = __builtin_nontemporal_load((const f32x4*)(hp + 12));
        half8 p0, p1;
        p0[0] = (_Float16)x0[0]; p0[1] = (_Float16)x0[1];
        p0[2] = (_Float16)x0[2]; p0[3] = (_Float16)x0[3];
        p0[4] = (_Float16)x1[0]; p0[5] = (_Float16)x1[1];
        p0[6] = (_Float16)x1[2]; p0[7] = (_Float16)x1[3];
        p1[0] = (_Float16)x2[0]; p1[1] = (_Float16)x2[1];
        p1[2] = (_Float16)x2[2]; p1[3] = (_Float16)x2[3];
        p1[4] = (_Float16)x3[0]; p1[5] = (_Float16)x3[1];
        p1[6] = (_Float16)x3[2]; p1[7] = (_Float16)x3[3];
        *(half8*)&sA[row * 72 + k0]     = p0;
        *(half8*)&sA[row * 72 + k0 + 8] = p1;
    }
    __syncthreads();

    // ---- A fragments from LDS: rows rt*16+cl, k = ks*32 + lg*8 + j
    half8 af[4][2];
    #pragma unroll
    for (int rt = 0; rt < 4; rt++)
        #pragma unroll
        for (int ks = 0; ks < 2; ks++)
            af[rt][ks] = *(half8*)&sA[(rt * 16 + cl) * 72 + ks * 32 + lg * 8];

    // ---- B fragments from Wt: slot = w*32 + ct*16 + cl
    half8 bf[2][2];
    #pragma unroll
    for (int ct = 0; ct < 2; ct++)
        #pragma unroll
        for (int ks = 0; ks < 2; ks++)
            bf[ct][ks] = *(const half8*)&Wt[(size_t)(w * 32 + ct * 16 + cl) * 64 + ks * 32 + lg * 8];

    // ---- score B fragment: col = q (0..3), rest zero
    half8 bq[2];
    #pragma unroll
    for (int ks = 0; ks < 2; ks++) {
        half8 b = {};
        if (cl < 4) b = *(const half8*)&WQt[cl * 64 + ks * 32 + lg * 8];
        bq[ks] = b;
    }

    __syncthreads();   // all A reads drained; smem is reusable as sOut

    // ---- MFMA main; D col index == output slot ei directly (Wt permuted)
    #pragma unroll
    for (int rt = 0; rt < 4; rt++)
        #pragma unroll
        for (int ct = 0; ct < 2; ct++) {
            f32x4 c = {0.f, 0.f, 0.f, 0.f};
            c = __builtin_amdgcn_mfma_f32_16x16x32_f16(af[rt][0], bf[ct][0], c, 0, 0, 0);
            c = __builtin_amdgcn_mfma_f32_16x16x32_f16(af[rt][1], bf[ct][1], c, 0, 0, 0);
            int slot = w * 32 + ct * 16 + cl;
            #pragma unroll
            for (int reg = 0; reg < 4; reg++)
                sOut[(rt * 16 + lg * 4 + reg) * 136 + slot] = (_Float16)c[reg];
        }

    // ---- score tile: wave w handles rowtile w
    f32x4 sacc = {0.f, 0.f, 0.f, 0.f};
    sacc = __builtin_amdgcn_mfma_f32_16x16x32_f16(af[w][0], bq[0], sacc, 0, 0, 0);
    sacc = __builtin_amdgcn_mfma_f32_16x16x32_f16(af[w][1], bq[1], sacc, 0, 0, 0);

    float* ast = a_s + (size_t)t * N * 2;
    float* adt = a_d + (size_t)t * N * 2;
    if (cl < 4) {
        float* basep = (cl & 2) ? adt : ast;
        #pragma unroll
        for (int reg = 0; reg < 4; reg++) {
            int n = node0 + w * 16 + lg * 4 + reg;
            if (n < N) basep[(size_t)n * 2 + (cl & 1)] = sacc[reg];
        }
    }

    __syncthreads();

    // ---- coalesced store of xlh from sOut
    _Float16* xlt = xlh + (size_t)t * N * HC;
    #pragma unroll
    for (int it = 0; it < 4; it++) {
        int idx = it * 256 + tid;        // 1024 chunks of 8 f16
        int row = idx >> 4;
        int seg = idx & 15;
        int n = node0 + row;
        if (n < N)
            *(half8*)&xlt[(size_t)n * HC + seg * 8] = *(half8*)&sOut[row * 136 + seg * 8];
    }
}

// ---------------- Edge softmax + aggregate ----------------------------------
// blockIdx.y = timestep. 4 nodes per wave (16 lanes each), width-16 butterflies.
// Edge descriptors {src_byte_offset, half2(w0,w1)} staged in LDS, padded to
// mult of 8 with zero-weight entries (row 0, L1-hot); aggregation unrolled x8
// -> 8 independent gathers in flight. Per-edge math: one v_dot2_f32_f16.
// out stores are nontemporal (write-once, keep L2 for xlh gathers).
__global__ __launch_bounds__(256) void k_edge(
    const int* __restrict__ csr_row, const int* __restrict__ csr_src,
    const float* __restrict__ a_s, const float* __restrict__ a_d,
    const _Float16* __restrict__ xlh, const float* __restrict__ bias,
    float* __restrict__ out, int N)
{
    __shared__ int2 edata[16][16];   // [node_local][edge_j] = {src<<8, half2(w0,w1)}

    int tid  = threadIdx.x;
    int lane = tid & 63;
    int wid  = tid >> 6;
    int grp  = lane >> 4;    // 0..3: node slot within wave
    int gl   = lane & 15;    // lane within group
    int t = blockIdx.y;
    const _Float16* xlt = xlh + (size_t)t * N * HC;
    const char* xb = (const char*)xlt;
    int l4 = lane * 4;
    const float* ast = a_s + (size_t)t * N * 2;
    const float* adt = a_d + (size_t)t * N * 2;

    int nodeBlock0 = blockIdx.x * 16;
    int node = nodeBlock0 + wid * 4 + grp;
    bool nvalid = node < N;

    int beg = 0, end = 0;
    if (nvalid) { beg = csr_row[node]; end = csr_row[node + 1]; }
    int deg = end - beg;

    float bs = bias[lane];

    if (__ballot(deg > 16) == 0ull) {
        // ---- fast path: deg <= 16 for all 4 nodes of this wave ----
        float2 adv = make_float2(0.f, 0.f);
        if (nvalid) adv = *(const float2*)&adt[(size_t)node * 2];

        int e = beg + gl;
        bool ev = nvalid && (e < end);
        int s = ev ? csr_src[e] : 0;
        float e0 = -1e30f, e1 = -1e30f;
        if (ev) {
            float2 asv = *(const float2*)&ast[(size_t)s * 2];
            e0 = asv.x + adv.x;
            e1 = asv.y + adv.y;
            e0 = e0 > 0.f ? e0 : NEG_SLOPE * e0;
            e1 = e1 > 0.f ? e1 : NEG_SLOPE * e1;
        }
        float m0 = e0, m1 = e1;
        #pragma unroll
        for (int off = 8; off >= 1; off >>= 1) {
            m0 = fmaxf(m0, __shfl_xor(m0, off));
            m1 = fmaxf(m1, __shfl_xor(m1, off));
        }
        float x0 = ev ? __expf(e0 - m0) : 0.f;
        float x1 = ev ? __expf(e1 - m1) : 0.f;
        float d0 = x0, d1 = x1;
        #pragma unroll
        for (int off = 8; off >= 1; off >>= 1) {
            d0 += __shfl_xor(d0, off);
            d1 += __shfl_xor(d1, off);
        }
        float w0 = x0 * (0.5f / d0);   // 0.5 = head-mean
        float w1 = x1 * (0.5f / d1);

        // all 16 slots written: invalid lanes write zero-weight entries (off 0)
        union { uint u; _Float16 hh[2]; } cw;
        cw.hh[0] = ev ? (_Float16)w0 : (_Float16)0.f;
        cw.hh[1] = ev ? (_Float16)w1 : (_Float16)0.f;
        edata[wid * 4 + grp][gl] = make_int2(ev ? (s << 8) : 0, (int)cw.u);
        // wave-synchronous: same wave wrote the rows it reads below

        #pragma unroll
        for (int k = 0; k < 4; k++) {
            int nk = nodeBlock0 + wid * 4 + k;
            if (nk >= N) continue;
            int dk = __shfl(deg, k * 16);
            int dkr = (dk + 7) & ~7;          // padded entries have w=0
            float a0 = 0.f, a1 = 0.f;
            const int2* row = edata[wid * 4 + k];
            for (int j = 0; j < dkr; j += 8) {
                int4 p  = *(const int4*)&row[j];       // edges j..j+1
                int4 q  = *(const int4*)&row[j + 2];   // edges j+2..j+3
                int4 r2 = *(const int4*)&row[j + 4];   // edges j+4..j+5
                int4 s2 = *(const int4*)&row[j + 6];   // edges j+6..j+7
                half2v v0 = *(const half2v*)(xb + p.x  + l4);
                half2v v1 = *(const half2v*)(xb + p.z  + l4);
                half2v v2 = *(const half2v*)(xb + q.x  + l4);
                half2v v3 = *(const half2v*)(xb + q.z  + l4);
                half2v v4 = *(const half2v*)(xb + r2.x + l4);
                half2v v5 = *(const half2v*)(xb + r2.z + l4);
                half2v v6 = *(const half2v*)(xb + s2.x + l4);
                half2v v7 = *(const half2v*)(xb + s2.z + l4);
                union { int i; half2v h; } c0, c1, c2, c3, c4, c5, c6, c7;
                c0.i = p.y;  c1.i = p.w;
                c2.i = q.y;  c3.i = q.w;
                c4.i = r2.y; c5.i = r2.w;
                c6.i = s2.y; c7.i = s2.w;
                a0 = dot2(v0, c0.h, a0);
                a1 = dot2(v1, c1.h, a1);
                a0 = dot2(v2, c2.h, a0);
                a1 = dot2(v3, c3.h, a1);
                a0 = dot2(v4, c4.h, a0);
                a1 = dot2(v5, c5.h, a1);
                a0 = dot2(v6, c6.h, a0);
                a1 = dot2(v7, c7.h, a1);
            }
            float acc = a0 + a1 + bs;
            float o = acc > 0.f ? acc : expm1f(acc);
            __builtin_nontemporal_store(o, &out[((size_t)nk * T_STEPS + t) * C_OUT + lane]);
        }
    } else {
        // ---- generic path: 64-wide strided per node, 4 nodes sequentially ----
        #pragma unroll
        for (int k = 0; k < 4; k++) {
            int nk = nodeBlock0 + wid * 4 + k;
            if (nk >= N) continue;
            int bk = __shfl(beg, k * 16);
            int ek = __shfl(end, k * 16);
            float2 adv = *(const float2*)&adt[(size_t)nk * 2];

            float m0 = -1e30f, m1 = -1e30f;
            for (int e = bk + lane; e < ek; e += 64) {
                int s = csr_src[e];
                float2 asv = *(const float2*)&ast[(size_t)s * 2];
                float e0 = asv.x + adv.x, e1 = asv.y + adv.y;
                e0 = e0 > 0.f ? e0 : NEG_SLOPE * e0;
                e1 = e1 > 0.f ? e1 : NEG_SLOPE * e1;
                m0 = fmaxf(m0, e0); m1 = fmaxf(m1, e1);
            }
            #pragma unroll
            for (int off = 32; off >= 1; off >>= 1) {
                m0 = fmaxf(m0, __shfl_xor(m0, off));
                m1 = fmaxf(m1, __shfl_xor(m1, off));
            }
            float d0 = 0.f, d1 = 0.f;
            for (int e = bk + lane; e < ek; e += 64) {
                int s = csr_src[e];
                float2 asv = *(const float2*)&ast[(size_t)s * 2];
                float e0 = asv.x + adv.x, e1 = asv.y + adv.y;
                e0 = e0 > 0.f ? e0 : NEG_SLOPE * e0;
                e1 = e1 > 0.f ? e1 : NEG_SLOPE * e1;
                d0 += __expf(e0 - m0); d1 += __expf(e1 - m1);
            }
            #pragma unroll
            for (int off = 32; off >= 1; off >>= 1) {
                d0 += __shfl_xor(d0, off);
                d1 += __shfl_xor(d1, off);
            }
            float r0 = 0.5f / d0, r1 = 0.5f / d1;

            float a0 = 0.f, a1 = 0.f;
            for (int base = bk; base < ek; base += 64) {
                int e = base + lane;
                int cnt = min(64, ek - base);
                int soff = 0;
                union { uint u; _Float16 hh[2]; } cw;
                cw.u = 0u;
                if (e < ek) {
                    int s = csr_src[e];
                    soff = s << 8;
                    float2 asv = *(const float2*)&ast[(size_t)s * 2];
                    float e0 = asv.x + adv.x, e1 = asv.y + adv.y;
                    e0 = e0 > 0.f ? e0 : NEG_SLOPE * e0;
                    e1 = e1 > 0.f ? e1 : NEG_SLOPE * e1;
                    cw.hh[0] = (_Float16)(__expf(e0 - m0) * r0);
                    cw.hh[1] = (_Float16)(__expf(e1 - m1) * r1);
                }
                int wv = (int)cw.u;
                for (int j = 0; j < cnt; j++) {
                    int sj = __shfl(soff, j);
                    int wj = __shfl(wv, j);
                    union { int i; half2v h; } c; c.i = wj;
                    half2v v = *(const half2v*)(xb + sj + l4);
                    a0 = dot2(v, c.h, a0);
                }
            }
            float acc = a0 + a1 + bs;
            float o = acc > 0.f ? acc : expm1f(acc);
            __builtin_nontemporal_store(o, &out[((size_t)nk * T_STEPS + t) * C_OUT + lane]);
        }
    }
}

// ---------------- launcher ----------------
extern "C" void kernel_launch(void* const* d_in, const int* in_sizes, int n_in,
                              void* d_out, int out_size, void* d_ws, size_t ws_size,
                              hipStream_t stream)
{
    const float* h       = (const float*)d_in[0];
    const int*   src     = (const int*)d_in[1];
    const int*   dst     = (const int*)d_in[2];
    const float* W       = (const float*)d_in[3];
    const float* att_src = (const float*)d_in[4];
    const float* att_dst = (const float*)d_in[5];
    const float* bias    = (const float*)d_in[6];
    float* out = (float*)d_out;

    int N = in_sizes[0] / (T_STEPS * F_IN);
    int E = in_sizes[1];

    char* wsb = (char*)d_ws;
    size_t off = 0;
    auto alloc = [&](size_t bytes) -> char* {
        off = (off + 255) & ~(size_t)255;
        char* p = wsb + off;
        off += bytes;
        return p;
    };

    int* csr_row = (int*)alloc((size_t)(N + 1) * sizeof(int));
    int* cursor  = (int*)alloc((size_t)N * sizeof(int));
    int* bsum    = (int*)alloc(1024 * sizeof(int));
    int* csr_src = (int*)alloc((size_t)E * sizeof(int));
    float* a_s   = (float*)alloc((size_t)T_STEPS * N * 2 * sizeof(float));
    float* a_d   = (float*)alloc((size_t)T_STEPS * N * 2 * sizeof(float));
    _Float16* Wt  = (_Float16*)alloc((size_t)HC * 64 * sizeof(_Float16));
    _Float16* WQt = (_Float16*)alloc(4 * 64 * sizeof(_Float16));
    _Float16* xlh = (_Float16*)alloc((size_t)T_STEPS * N * HC * sizeof(_Float16));
    // total ~110 MB; all-t fp16 xlh (102 MB) fits L3 (256 MB)

    int nb = (N + 255) / 256;
    k_zero_i32<<<(N + 1 + 255) / 256, 256, 0, stream>>>(csr_row, N + 1);
    k_count<<<(E + 255) / 256, 256, 0, stream>>>(dst, csr_row, E);
    k_scan1<<<nb, 256, 0, stream>>>(csr_row, bsum, N);
    k_scan2<<<1, 256, 0, stream>>>(bsum, nb);
    k_scan3<<<nb, 256, 0, stream>>>(csr_row, bsum, cursor, N, E);
    k_fill<<<(E + 255) / 256, 256, 0, stream>>>(src, dst, cursor, csr_src, E);

    k_prep<<<33, 256, 0, stream>>>(W, att_src, att_dst, Wt, WQt);
    dim3 gg((N + 63) / 64, T_STEPS);
    k_gemm<<<gg, 256, 0, stream>>>(h, Wt, WQt, xlh, a_s, a_d, N);
    dim3 ge((N + 15) / 16, T_STEPS);
    k_edge<<<ge, 256, 0, stream>>>(csr_row, csr_src, a_s, a_d, xlh, bias, out, N);
}

// Round 7
// 418.548 us; speedup vs baseline: 1.1678x; 1.0509x over previous
//
#include <hip/hip_runtime.h>
#include <hip/hip_bf16.h>
#include <math.h>

#define T_STEPS 8
#define F_IN 64
#define HC 128        // H*C = 2*64
#define C_OUT 64
#define NEG_SLOPE 0.2f

typedef _Float16 half8 __attribute__((ext_vector_type(8)));
typedef _Float16 half2v __attribute__((ext_vector_type(2)));
typedef float f32x4 __attribute__((ext_vector_type(4)));

// packed f16 dot: acc += a.x*b.x + a.y*b.y (f32 accumulate) — V_DOT2_F32_F16
static __device__ __forceinline__ float dot2(half2v a, half2v b, float c) {
    return __builtin_amdgcn_fdot2(a, b, c, false);
}

// ---------------- CSR build ----------------
__global__ void k_zero_i32(int* p, int n) {
    int i = blockIdx.x * blockDim.x + threadIdx.x;
    if (i < n) p[i] = 0;
}

__global__ void k_count(const int* __restrict__ dst, int* __restrict__ cnt, int E) {
    int e = blockIdx.x * blockDim.x + threadIdx.x;
    if (e < E) atomicAdd(&cnt[dst[e]], 1);
}

__global__ void k_scan1(int* data, int* bsum, int n) {
    __shared__ int tmp[256];
    int tid = threadIdx.x;
    int i = blockIdx.x * 256 + tid;
    int v = (i < n) ? data[i] : 0;
    tmp[tid] = v; __syncthreads();
    for (int off = 1; off < 256; off <<= 1) {
        int x = (tid >= off) ? tmp[tid - off] : 0;
        __syncthreads();
        tmp[tid] += x;
        __syncthreads();
    }
    if (i < n) data[i] = tmp[tid] - v;   // exclusive
    if (tid == 255) bsum[blockIdx.x] = tmp[255];
}

__global__ void k_scan2(int* bsum, int nb) {  // nb <= 256
    __shared__ int tmp[256];
    int tid = threadIdx.x;
    int v = (tid < nb) ? bsum[tid] : 0;
    tmp[tid] = v; __syncthreads();
    for (int off = 1; off < 256; off <<= 1) {
        int x = (tid >= off) ? tmp[tid - off] : 0;
        __syncthreads();
        tmp[tid] += x;
        __syncthreads();
    }
    if (tid < nb) bsum[tid] = tmp[tid] - v;
}

__global__ void k_scan3(int* data, const int* __restrict__ bsum, int* cursor, int n, int total) {
    int i = blockIdx.x * 256 + threadIdx.x;
    if (i < n) {
        int v = data[i] + bsum[i >> 8];
        data[i] = v;
        cursor[i] = v;
    }
    if (i == 0) data[n] = total;
}

__global__ void k_fill(const int* __restrict__ src, const int* __restrict__ dst,
                       int* __restrict__ cursor, int* __restrict__ csr_src, int E) {
    int e = blockIdx.x * blockDim.x + threadIdx.x;
    if (e < E) {
        int d = dst[e];
        int pos = atomicAdd(&cursor[d], 1);
        csr_src[pos] = src[e];
    }
}

// ---------------- prep: WQt [4][64] f16 and Wt [128][64] f16 ----------------
// WQt[q][f] = sum_c W[f][head(q)*64+c]*att_q[c]; q: 0=(s,h0) 1=(s,h1) 2=(d,h0) 3=(d,h1)
// Wt[ei][k] = W[k][ (ei&1)*64 + (ei>>1) ]  (head-interleaved output slot ei)
// 33 blocks: block 0 -> WQt, blocks 1..32 -> Wt (256 elements each)
__global__ void k_prep(const float* __restrict__ W, const float* __restrict__ att_src,
                       const float* __restrict__ att_dst,
                       _Float16* __restrict__ Wt, _Float16* __restrict__ WQt) {
    int b = blockIdx.x;
    int tid = threadIdx.x;         // 256 threads
    if (b == 0) {
        int q = tid & 3, f = tid >> 2; // f in 0..63
        const float* att = (q & 2) ? att_dst : att_src;
        int hh = q & 1;
        float s = 0.f;
        #pragma unroll 8
        for (int c = 0; c < 64; c++) s += W[f * HC + hh * 64 + c] * att[hh * 64 + c];
        WQt[q * 64 + f] = (_Float16)s;
    } else {
        int i = (b - 1) * 256 + tid;   // 32*256 = 8192 = 64*HC
        int ei = i >> 6, k = i & 63;
        Wt[i] = (_Float16)W[k * HC + (ei & 1) * 64 + (ei >> 1)];
    }
}

// ---------------- GEMM via MFMA: xl = x_t @ W (fp16 head-interleaved) + scores
// blockIdx.y = timestep. 64 nodes x 128 slots per block, 4 waves (32 slots each).
// A staged once through LDS (f16, 72-pad), B fragments = vector loads from the
// precomputed Wt (L1-resident). Output staged in 136-pad LDS (<=2-way banks).
// mfma_f32_16x16x32_f16: A[row=lane%16][k=(lane/16)*8+j],
// B[k=(lane/16)*8+j][col=lane%16], D[col=lane&15][row=(lane>>4)*4+reg].
__global__ __launch_bounds__(256) void k_gemm(
    const float* __restrict__ h, const _Float16* __restrict__ Wt,
    const _Float16* __restrict__ WQt,
    _Float16* __restrict__ xlh, float* __restrict__ a_s, float* __restrict__ a_d,
    int N)
{
    __shared__ _Float16 smem[64 * 136];  // 17408 B, overlaid: sA [64][72] then sOut [64][136]
    _Float16* sA   = smem;
    _Float16* sOut = smem;

    int tid = threadIdx.x;
    int t = blockIdx.y;
    int node0 = blockIdx.x * 64;
    int w = tid >> 6;          // wave 0..3 -> slot slice w*32
    int lane = tid & 63;
    int cl = lane & 15;
    int lg = lane >> 4;

    // ---- stage A: h[node0+row][t][k] -> f16 sA[row][k], row pad 72
    {
        int row = tid >> 2;
        int k0 = (tid & 3) * 16;
        int n = node0 + row;
        int nc = n < N ? n : N - 1;          // clamp reads; stores guarded later
        const float* hp = h + ((size_t)nc * T_STEPS + t) * F_IN + k0;
        f32x4 x0 = __builtin_nontemporal_load((const f32x4*)(hp));
        f32x4 x1 = __builtin_nontemporal_load((const f32x4*)(hp + 4));
        f32x4 x2 = __builtin_nontemporal_load((const f32x4*)(hp + 8));
        f32x4 x3 = __builtin_nontemporal_load((const f32x4*)(hp + 12));
        half8 p0, p1;
        p0[0] = (_Float16)x0[0]; p0[1] = (_Float16)x0[1];
        p0[2] = (_Float16)x0[2]; p0[3] = (_Float16)x0[3];
        p0[4] = (_Float16)x1[0]; p0[5] = (_Float16)x1[1];
        p0[6] = (_Float16)x1[2]; p0[7] = (_Float16)x1[3];
        p1[0] = (_Float16)x2[0]; p1[1] = (_Float16)x2[1];
        p1[2] = (_Float16)x2[2]; p1[3] = (_Float16)x2[3];
        p1[4] = (_Float16)x3[0]; p1[5] = (_Float16)x3[1];
        p1[6] = (_Float16)x3[2]; p1[7] = (_Float16)x3[3];
        *(half8*)&sA[row * 72 + k0]     = p0;
        *(half8*)&sA[row * 72 + k0 + 8] = p1;
    }
    __syncthreads();

    // ---- A fragments from LDS: rows rt*16+cl, k = ks*32 + lg*8 + j
    half8 af[4][2];
    #pragma unroll
    for (int rt = 0; rt < 4; rt++)
        #pragma unroll
        for (int ks = 0; ks < 2; ks++)
            af[rt][ks] = *(half8*)&sA[(rt * 16 + cl) * 72 + ks * 32 + lg * 8];

    // ---- B fragments from Wt: slot = w*32 + ct*16 + cl
    half8 bf[2][2];
    #pragma unroll
    for (int ct = 0; ct < 2; ct++)
        #pragma unroll
        for (int ks = 0; ks < 2; ks++)
            bf[ct][ks] = *(const half8*)&Wt[(size_t)(w * 32 + ct * 16 + cl) * 64 + ks * 32 + lg * 8];

    // ---- score B fragment: col = q (0..3), rest zero
    half8 bq[2];
    #pragma unroll
    for (int ks = 0; ks < 2; ks++) {
        half8 b = {};
        if (cl < 4) b = *(const half8*)&WQt[cl * 64 + ks * 32 + lg * 8];
        bq[ks] = b;
    }

    __syncthreads();   // all A reads drained; smem is reusable as sOut

    // ---- MFMA main; D col index == output slot ei directly (Wt permuted)
    #pragma unroll
    for (int rt = 0; rt < 4; rt++)
        #pragma unroll
        for (int ct = 0; ct < 2; ct++) {
            f32x4 c = {0.f, 0.f, 0.f, 0.f};
            c = __builtin_amdgcn_mfma_f32_16x16x32_f16(af[rt][0], bf[ct][0], c, 0, 0, 0);
            c = __builtin_amdgcn_mfma_f32_16x16x32_f16(af[rt][1], bf[ct][1], c, 0, 0, 0);
            int slot = w * 32 + ct * 16 + cl;
            #pragma unroll
            for (int reg = 0; reg < 4; reg++)
                sOut[(rt * 16 + lg * 4 + reg) * 136 + slot] = (_Float16)c[reg];
        }

    // ---- score tile: wave w handles rowtile w
    f32x4 sacc = {0.f, 0.f, 0.f, 0.f};
    sacc = __builtin_amdgcn_mfma_f32_16x16x32_f16(af[w][0], bq[0], sacc, 0, 0, 0);
    sacc = __builtin_amdgcn_mfma_f32_16x16x32_f16(af[w][1], bq[1], sacc, 0, 0, 0);

    float* ast = a_s + (size_t)t * N * 2;
    float* adt = a_d + (size_t)t * N * 2;
    if (cl < 4) {
        float* basep = (cl & 2) ? adt : ast;
        #pragma unroll
        for (int reg = 0; reg < 4; reg++) {
            int n = node0 + w * 16 + lg * 4 + reg;
            if (n < N) basep[(size_t)n * 2 + (cl & 1)] = sacc[reg];
        }
    }

    __syncthreads();

    // ---- coalesced store of xlh from sOut
    _Float16* xlt = xlh + (size_t)t * N * HC;
    #pragma unroll
    for (int it = 0; it < 4; it++) {
        int idx = it * 256 + tid;        // 1024 chunks of 8 f16
        int row = idx >> 4;
        int seg = idx & 15;
        int n = node0 + row;
        if (n < N)
            *(half8*)&xlt[(size_t)n * HC + seg * 8] = *(half8*)&sOut[row * 136 + seg * 8];
    }
}

// ---------------- Edge softmax + aggregate ----------------------------------
// blockIdx.y = timestep. 16 nodes/block, 4 nodes/wave. Fast path: each 16-lane
// group processes ITS OWN node's edges in parallel. Lane s of a group owns
// channels s*4..s*4+3 and gathers its 16 B of the source row with one b128
// load; weights broadcast from LDS; 4 dot2/edge accumulate channels fully
// in-lane -> bias+ELU+f32x4 nontemporal store, no cross-lane reduce.
// Cap 32 edges. edata rows padded to 34 int2 (272 B).
__global__ __launch_bounds__(256) void k_edge(
    const int* __restrict__ csr_row, const int* __restrict__ csr_src,
    const float* __restrict__ a_s, const float* __restrict__ a_d,
    const _Float16* __restrict__ xlh, const float* __restrict__ bias,
    float* __restrict__ out, int N)
{
    __shared__ int2 edata[16][34];   // [node_local][edge_j] = {src<<8, half2(w0,w1)}

    int tid  = threadIdx.x;
    int lane = tid & 63;
    int wid  = tid >> 6;
    int grp  = lane >> 4;    // 0..3: node slot within wave
    int gl   = lane & 15;    // lane within group
    int t = blockIdx.y;
    const _Float16* xlt = xlh + (size_t)t * N * HC;
    const char* xb = (const char*)xlt;
    const float* ast = a_s + (size_t)t * N * 2;
    const float* adt = a_d + (size_t)t * N * 2;

    int nodeBlock0 = blockIdx.x * 16;
    int node = nodeBlock0 + wid * 4 + grp;
    bool nvalid = node < N;

    int beg = 0, end = 0;
    if (nvalid) { beg = csr_row[node]; end = csr_row[node + 1]; }
    int deg = end - beg;

    if (__ballot(deg > 32) == 0ull) {
        // ---- fast path: deg <= 32 for all 4 nodes of this wave ----
        float2 adv = make_float2(0.f, 0.f);
        if (nvalid) adv = *(const float2*)&adt[(size_t)node * 2];

        // two candidate edges per lane (slots gl and gl+16)
        int ea = beg + gl, eb = beg + gl + 16;
        bool eva = nvalid && (ea < end);
        bool evb = nvalid && (eb < end);
        int sa = eva ? csr_src[ea] : 0;
        int sb = evb ? csr_src[eb] : 0;
        float ea0 = -1e30f, ea1 = -1e30f, eb0 = -1e30f, eb1 = -1e30f;
        if (eva) {
            float2 v = *(const float2*)&ast[(size_t)sa * 2];
            ea0 = v.x + adv.x; ea1 = v.y + adv.y;
            ea0 = ea0 > 0.f ? ea0 : NEG_SLOPE * ea0;
            ea1 = ea1 > 0.f ? ea1 : NEG_SLOPE * ea1;
        }
        if (evb) {
            float2 v = *(const float2*)&ast[(size_t)sb * 2];
            eb0 = v.x + adv.x; eb1 = v.y + adv.y;
            eb0 = eb0 > 0.f ? eb0 : NEG_SLOPE * eb0;
            eb1 = eb1 > 0.f ? eb1 : NEG_SLOPE * eb1;
        }
        float m0 = fmaxf(ea0, eb0), m1 = fmaxf(ea1, eb1);
        #pragma unroll
        for (int off = 8; off >= 1; off >>= 1) {
            m0 = fmaxf(m0, __shfl_xor(m0, off));
            m1 = fmaxf(m1, __shfl_xor(m1, off));
        }
        float xa0 = eva ? __expf(ea0 - m0) : 0.f;
        float xa1 = eva ? __expf(ea1 - m1) : 0.f;
        float xb0 = evb ? __expf(eb0 - m0) : 0.f;
        float xb1 = evb ? __expf(eb1 - m1) : 0.f;
        float d0 = xa0 + xb0, d1 = xa1 + xb1;
        #pragma unroll
        for (int off = 8; off >= 1; off >>= 1) {
            d0 += __shfl_xor(d0, off);
            d1 += __shfl_xor(d1, off);
        }
        float r0 = 0.5f / d0, r1 = 0.5f / d1;   // 0.5 = head-mean

        union { uint u; _Float16 hh[2]; } cwa, cwb;
        cwa.hh[0] = (_Float16)(xa0 * r0); cwa.hh[1] = (_Float16)(xa1 * r1);
        cwb.hh[0] = (_Float16)(xb0 * r0); cwb.hh[1] = (_Float16)(xb1 * r1);
        int myrow = wid * 4 + grp;
        edata[myrow][gl]      = make_int2(eva ? (sa << 8) : 0, (int)cwa.u);
        edata[myrow][gl + 16] = make_int2(evb ? (sb << 8) : 0, (int)cwb.u);
        // wave-synchronous: same wave wrote the rows it reads below

        // wave-max degree, padded to multiple of 4 (pad slots have w=0, row 0)
        int wmax = deg;
        wmax = max(wmax, __shfl_xor(wmax, 16));
        wmax = max(wmax, __shfl_xor(wmax, 32));
        int dkr = (wmax + 3) & ~3;

        const int2* row = edata[myrow];
        int sb16 = gl * 16;          // byte offset of this lane's 16B channel slice
        float ac0 = 0.f, ac1 = 0.f, ac2 = 0.f, ac3 = 0.f;
        union h8u { half8 v; half2v h[4]; };
        for (int j = 0; j < dkr; j += 4) {
            int4 p = *(const int4*)&row[j];       // edges j, j+1
            int4 q = *(const int4*)&row[j + 2];   // edges j+2, j+3
            h8u v0, v1, v2, v3;
            v0.v = *(const half8*)(xb + p.x + sb16);
            v1.v = *(const half8*)(xb + p.z + sb16);
            v2.v = *(const half8*)(xb + q.x + sb16);
            v3.v = *(const half8*)(xb + q.z + sb16);
            union { int i; half2v h; } w0, w1, w2, w3;
            w0.i = p.y; w1.i = p.w; w2.i = q.y; w3.i = q.w;
            ac0 = dot2(v0.h[0], w0.h, ac0);
            ac1 = dot2(v0.h[1], w0.h, ac1);
            ac2 = dot2(v0.h[2], w0.h, ac2);
            ac3 = dot2(v0.h[3], w0.h, ac3);
            ac0 = dot2(v1.h[0], w1.h, ac0);
            ac1 = dot2(v1.h[1], w1.h, ac1);
            ac2 = dot2(v1.h[2], w1.h, ac2);
            ac3 = dot2(v1.h[3], w1.h, ac3);
            ac0 = dot2(v2.h[0], w2.h, ac0);
            ac1 = dot2(v2.h[1], w2.h, ac1);
            ac2 = dot2(v2.h[2], w2.h, ac2);
            ac3 = dot2(v2.h[3], w2.h, ac3);
            ac0 = dot2(v3.h[0], w3.h, ac0);
            ac1 = dot2(v3.h[1], w3.h, ac1);
            ac2 = dot2(v3.h[2], w3.h, ac2);
            ac3 = dot2(v3.h[3], w3.h, ac3);
        }
        if (nvalid) {
            float4 bv = *(const float4*)&bias[gl * 4];
            float c0 = ac0 + bv.x, c1 = ac1 + bv.y, c2 = ac2 + bv.z, c3 = ac3 + bv.w;
            f32x4 o;
            o[0] = c0 > 0.f ? c0 : expm1f(c0);
            o[1] = c1 > 0.f ? c1 : expm1f(c1);
            o[2] = c2 > 0.f ? c2 : expm1f(c2);
            o[3] = c3 > 0.f ? c3 : expm1f(c3);
            __builtin_nontemporal_store(o,
                (f32x4*)&out[((size_t)node * T_STEPS + t) * C_OUT + gl * 4]);
        }
    } else {
        // ---- generic path: 64-wide strided per node, 4 nodes sequentially ----
        float bs = bias[lane];
        #pragma unroll
        for (int k = 0; k < 4; k++) {
            int nk = nodeBlock0 + wid * 4 + k;
            if (nk >= N) continue;
            int bk = __shfl(beg, k * 16);
            int ek = __shfl(end, k * 16);
            float2 adv = *(const float2*)&adt[(size_t)nk * 2];

            float m0 = -1e30f, m1 = -1e30f;
            for (int e = bk + lane; e < ek; e += 64) {
                int s = csr_src[e];
                float2 asv = *(const float2*)&ast[(size_t)s * 2];
                float e0 = asv.x + adv.x, e1 = asv.y + adv.y;
                e0 = e0 > 0.f ? e0 : NEG_SLOPE * e0;
                e1 = e1 > 0.f ? e1 : NEG_SLOPE * e1;
                m0 = fmaxf(m0, e0); m1 = fmaxf(m1, e1);
            }
            #pragma unroll
            for (int off = 32; off >= 1; off >>= 1) {
                m0 = fmaxf(m0, __shfl_xor(m0, off));
                m1 = fmaxf(m1, __shfl_xor(m1, off));
            }
            float d0 = 0.f, d1 = 0.f;
            for (int e = bk + lane; e < ek; e += 64) {
                int s = csr_src[e];
                float2 asv = *(const float2*)&ast[(size_t)s * 2];
                float e0 = asv.x + adv.x, e1 = asv.y + adv.y;
                e0 = e0 > 0.f ? e0 : NEG_SLOPE * e0;
                e1 = e1 > 0.f ? e1 : NEG_SLOPE * e1;
                d0 += __expf(e0 - m0); d1 += __expf(e1 - m1);
            }
            #pragma unroll
            for (int off = 32; off >= 1; off >>= 1) {
                d0 += __shfl_xor(d0, off);
                d1 += __shfl_xor(d1, off);
            }
            float r0 = 0.5f / d0, r1 = 0.5f / d1;

            float a0 = 0.f, a1 = 0.f;
            for (int base = bk; base < ek; base += 64) {
                int e = base + lane;
                int cnt = min(64, ek - base);
                int soff = 0;
                union { uint u; _Float16 hh[2]; } cw;
                cw.u = 0u;
                if (e < ek) {
                    int s = csr_src[e];
                    soff = s << 8;
                    float2 asv = *(const float2*)&ast[(size_t)s * 2];
                    float e0 = asv.x + adv.x, e1 = asv.y + adv.y;
                    e0 = e0 > 0.f ? e0 : NEG_SLOPE * e0;
                    e1 = e1 > 0.f ? e1 : NEG_SLOPE * e1;
                    cw.hh[0] = (_Float16)(__expf(e0 - m0) * r0);
                    cw.hh[1] = (_Float16)(__expf(e1 - m1) * r1);
                }
                int wv = (int)cw.u;
                for (int j = 0; j < cnt; j++) {
                    int sj = __shfl(soff, j);
                    int wj = __shfl(wv, j);
                    union { int i; half2v h; } c; c.i = wj;
                    half2v v = *(const half2v*)(xb + sj + lane * 4);
                    a0 = dot2(v, c.h, a0);
                }
            }
            float acc = a0 + a1 + bs;
            float o = acc > 0.f ? acc : expm1f(acc);
            __builtin_nontemporal_store(o, &out[((size_t)nk * T_STEPS + t) * C_OUT + lane]);
        }
    }
}

// ---------------- launcher ----------------
extern "C" void kernel_launch(void* const* d_in, const int* in_sizes, int n_in,
                              void* d_out, int out_size, void* d_ws, size_t ws_size,
                              hipStream_t stream)
{
    const float* h       = (const float*)d_in[0];
    const int*   src     = (const int*)d_in[1];
    const int*   dst     = (const int*)d_in[2];
    const float* W       = (const float*)d_in[3];
    const float* att_src = (const float*)d_in[4];
    const float* att_dst = (const float*)d_in[5];
    const float* bias    = (const float*)d_in[6];
    float* out = (float*)d_out;

    int N = in_sizes[0] / (T_STEPS * F_IN);
    int E = in_sizes[1];

    char* wsb = (char*)d_ws;
    size_t off = 0;
    auto alloc = [&](size_t bytes) -> char* {
        off = (off + 255) & ~(size_t)255;
        char* p = wsb + off;
        off += bytes;
        return p;
    };

    int* csr_row = (int*)alloc((size_t)(N + 1) * sizeof(int));
    int* cursor  = (int*)alloc((size_t)N * sizeof(int));
    int* bsum    = (int*)alloc(1024 * sizeof(int));
    int* csr_src = (int*)alloc((size_t)E * sizeof(int));
    float* a_s   = (float*)alloc((size_t)T_STEPS * N * 2 * sizeof(float));
    float* a_d   = (float*)alloc((size_t)T_STEPS * N * 2 * sizeof(float));
    _Float16* Wt  = (_Float16*)alloc((size_t)HC * 64 * sizeof(_Float16));
    _Float16* WQt = (_Float16*)alloc(4 * 64 * sizeof(_Float16));
    _Float16* xlh = (_Float16*)alloc((size_t)T_STEPS * N * HC * sizeof(_Float16));
    // total ~110 MB; all-t fp16 xlh (102 MB) fits L3 (256 MB)

    int nb = (N + 255) / 256;
    k_zero_i32<<<(N + 1 + 255) / 256, 256, 0, stream>>>(csr_row, N + 1);
    k_count<<<(E + 255) / 256, 256, 0, stream>>>(dst, csr_row, E);
    k_scan1<<<nb, 256, 0, stream>>>(csr_row, bsum, N);
    k_scan2<<<1, 256, 0, stream>>>(bsum, nb);
    k_scan3<<<nb, 256, 0, stream>>>(csr_row, bsum, cursor, N, E);
    k_fill<<<(E + 255) / 256, 256, 0, stream>>>(src, dst, cursor, csr_src, E);

    k_prep<<<33, 256, 0, stream>>>(W, att_src, att_dst, Wt, WQt);
    dim3 gg((N + 63) / 64, T_STEPS);
    k_gemm<<<gg, 256, 0, stream>>>(h, Wt, WQt, xlh, a_s, a_d, N);
    dim3 ge((N + 15) / 16, T_STEPS);
    k_edge<<<ge, 256, 0, stream>>>(csr_row, csr_src, a_s, a_d, xlh, bias, out, N);
}